// Round 1
// 668.446 us; speedup vs baseline: 1.0113x; 1.0113x over previous
//
#include <hip/hip_runtime.h>
#include <hip/hip_bf16.h>
#include <stdint.h>

#define N_NODES 50000
#define N_EDGES 500000
#define DIM 512

typedef unsigned short u16;
typedef unsigned int u32;
typedef __bf16 bf16x8 __attribute__((ext_vector_type(8)));
typedef float f32x4 __attribute__((ext_vector_type(4)));

static __device__ __forceinline__ u16 f2bf(float f) {
  union { __bf16 b; u16 u; } cv; cv.b = (__bf16)f; return cv.u;
}
static __device__ __forceinline__ float bf2f(u16 u) {
  union { u16 u; __bf16 b; } cv; cv.u = u; return (float)cv.b;
}

// ---------------- CSR build ----------------
// chunked scan: thread t sums deg[t*49 .. t*49+48], ladder over 1024 partials,
// then sequential prefix write-back per chunk.
__global__ __launch_bounds__(1024) void k_scan(const int* __restrict__ deg,
                                               int* __restrict__ offs,
                                               int* __restrict__ pos,
                                               float* __restrict__ invd) {
  __shared__ int sums[1024];
  const int tid = threadIdx.x;
  const int CH = 49;  // 1024*49 = 50176 >= 50000
  int lo = tid * CH;
  int hi = lo + CH; if (hi > N_NODES) hi = N_NODES;
  if (lo > N_NODES) lo = N_NODES;
  int s = 0;
  for (int i = lo; i < hi; ++i) s += deg[i];
  sums[tid] = s;
  __syncthreads();
  for (int off = 1; off < 1024; off <<= 1) {
    int t = (tid >= off) ? sums[tid - off] : 0;
    __syncthreads();
    sums[tid] += t;
    __syncthreads();
  }
  int run = sums[tid] - s;  // exclusive prefix of this chunk
  for (int i = lo; i < hi; ++i) {
    int d = deg[i];
    offs[i] = run; pos[i] = run;
    invd[i] = 1.0f / (float)((d > 1) ? d : 1);
    run += d;
  }
  if (tid == 1023) offs[N_NODES] = run;
}

// srcs stores src*DIM (u16-element offset) so agg skips the multiply
__global__ void k_scatter(const int* __restrict__ src, const int* __restrict__ dst,
                          int* __restrict__ pos, int* __restrict__ srcs) {
  int e = blockIdx.x * blockDim.x + threadIdx.x;
  if (e < N_EDGES) {
    int p = atomicAdd(&pos[dst[e]], 1);
    srcs[p] = src[e] * DIM;
  }
}

// ---------------- fused prep: cvt_x + edge histogram + 6x weight transpose ----
// grid 12500 x 256. Every thread does its cvt_x slice (3.2M threads exactly).
// Threads with t < N_EDGES also do the degree histogram (rides under cvt BW).
// The last 384 blocks additionally transpose one 64x64 tile of one weight
// matrix ([K=512][N=512] f32 -> [N][K] bf16 via LDS).
__global__ __launch_bounds__(256) void k_prep(
    const float* __restrict__ x, u16* __restrict__ xb,
    const int* __restrict__ dst, int* __restrict__ deg,
    const float* __restrict__ Wa, const float* __restrict__ Wb,
    const float* __restrict__ Wc, const float* __restrict__ Wd,
    const float* __restrict__ We, const float* __restrict__ Wf,
    u16* __restrict__ Oa, u16* __restrict__ Ob, u16* __restrict__ Oc,
    u16* __restrict__ Od, u16* __restrict__ Oe, u16* __restrict__ Of) {
  __shared__ u16 tbuf[64][66];
  const int t = blockIdx.x * 256 + threadIdx.x;

  // --- cvt_x: 8 floats -> 8 bf16 per thread ---
  const float4* p = (const float4*)(x + (size_t)t * 8);
  float4 a = p[0], b = p[1];
  uint4 o;
  o.x = (u32)f2bf(a.x) | ((u32)f2bf(a.y) << 16);
  o.y = (u32)f2bf(a.z) | ((u32)f2bf(a.w) << 16);
  o.z = (u32)f2bf(b.x) | ((u32)f2bf(b.y) << 16);
  o.w = (u32)f2bf(b.z) | ((u32)f2bf(b.w) << 16);
  *(uint4*)(xb + (size_t)t * 8) = o;

  // --- edge degree histogram ---
  if (t < N_EDGES) atomicAdd(&deg[dst[t]], 1);

  // --- weight transpose (last 384 blocks; disjoint from hist blocks) ---
  const int wb = (int)blockIdx.x - (12500 - 384);
  if (wb >= 0) {
    const float* W; u16* O;
    switch (wb / 64) {
      case 0: W = Wa; O = Oa; break;
      case 1: W = Wb; O = Ob; break;
      case 2: W = Wc; O = Oc; break;
      case 3: W = Wd; O = Od; break;
      case 4: W = We; O = Oe; break;
      default: W = Wf; O = Of; break;
    }
    const int rem = wb & 63;
    const int k0 = (rem & 7) * 64, n0 = (rem >> 3) * 64;
    const int lr = threadIdx.x & 63, wr = threadIdx.x >> 6;
#pragma unroll
    for (int rr = 0; rr < 16; ++rr) {
      int k = k0 + wr * 16 + rr;
      tbuf[lr][wr * 16 + rr] = f2bf(W[(size_t)k * 512 + n0 + lr]);
    }
    __syncthreads();
#pragma unroll
    for (int rr = 0; rr < 16; ++rr) {
      int n = n0 + wr * 16 + rr;
      O[(size_t)n * 512 + k0 + lr] = tbuf[wr * 16 + rr][lr];
    }
  }
}

// ---------------- aggregation: one wave per node, bf16 gather ----------------
// 4-wide edge unroll for memory-level parallelism; srcs pre-scaled by DIM.
#define ACC1(q)                                              \
  acc[0] += bf2f((q).x & 0xffff); acc[1] += bf2f((u16)((q).x >> 16)); \
  acc[2] += bf2f((q).y & 0xffff); acc[3] += bf2f((u16)((q).y >> 16)); \
  acc[4] += bf2f((q).z & 0xffff); acc[5] += bf2f((u16)((q).z >> 16)); \
  acc[6] += bf2f((q).w & 0xffff); acc[7] += bf2f((u16)((q).w >> 16));

__global__ __launch_bounds__(256) void k_agg_bf16(
    const u16* __restrict__ hb, const int* __restrict__ offs,
    const int* __restrict__ srcs, const float* __restrict__ invd,
    u16* __restrict__ outb) {
  int node = blockIdx.x * 4 + (threadIdx.x >> 6);
  int lane = threadIdx.x & 63;
  if (node >= N_NODES) return;
  int s0 = offs[node], s1 = offs[node + 1];
  float acc[8] = {0, 0, 0, 0, 0, 0, 0, 0};
  const u16* hl = hb + lane * 8;
  int i = s0;
  for (; i + 4 <= s1; i += 4) {
    int sa = srcs[i], sb = srcs[i + 1], sc = srcs[i + 2], sd = srcs[i + 3];
    uint4 qa = *(const uint4*)(hl + sa);
    uint4 qb = *(const uint4*)(hl + sb);
    uint4 qc = *(const uint4*)(hl + sc);
    uint4 qd = *(const uint4*)(hl + sd);
    ACC1(qa) ACC1(qb) ACC1(qc) ACC1(qd)
  }
  if (i + 2 <= s1) {
    int sa = srcs[i], sb = srcs[i + 1];
    uint4 qa = *(const uint4*)(hl + sa);
    uint4 qb = *(const uint4*)(hl + sb);
    ACC1(qa) ACC1(qb)
    i += 2;
  }
  if (i < s1) {
    int sa = srcs[i];
    uint4 qa = *(const uint4*)(hl + sa);
    ACC1(qa)
  }
  float iv = invd[node];
  uint4 o;
  o.x = (u32)f2bf(acc[0] * iv) | ((u32)f2bf(acc[1] * iv) << 16);
  o.y = (u32)f2bf(acc[2] * iv) | ((u32)f2bf(acc[3] * iv) << 16);
  o.z = (u32)f2bf(acc[4] * iv) | ((u32)f2bf(acc[5] * iv) << 16);
  o.w = (u32)f2bf(acc[6] * iv) | ((u32)f2bf(acc[7] * iv) << 16);
  *(uint4*)(outb + (size_t)node * DIM + lane * 8) = o;
}

// ---------------- GEMM: 256x256 tile, BK=64, 8 waves, 4-phase pipeline ----------
// C[M,512] = A1@W1t (+ A2@W2t) + bias.  A row-major [M,512] bf16;
// W pre-transposed [Nout=512][K=512] bf16.
// LDS 128KB: [buf0|buf1] x [A|B] x 256x64 bf16, XOR-chunk-swizzled rows.
// Striped halves: half h = 16-row groups with (group&1)==h, so every wave's
// phase-(ih,jh) quadrant needs exactly halves (A_h=ih, B_h=jh) -> wave-uniform
// counted-vmcnt waits:  issue order per tile (A0,B0,A1,B1), waits:
//   ph1 vmcnt(4) -> A0,B0 landed;  ph2 vmcnt(2) -> A1,B1 landed (vmcnt(0) last tile)
// EPI: 0 = relu -> bf16   1 = f32 + bf16 copy (no relu)
// EPI 3 = fused dual-head: blockIdx selects (W1,bias,outf) vs (W2,bias2,outf2),
//         relu -> f32, A = A1 for all tiles, grid = 196*4.
#define MFMA __builtin_amdgcn_mfma_f32_16x16x32_bf16

template <int EPI>
__global__ __launch_bounds__(512, 2) void k_gemm8(
    const u16* __restrict__ A1, const u16* __restrict__ W1,
    const u16* __restrict__ A2, const u16* __restrict__ W2,
    const float* __restrict__ bias, const float* __restrict__ bias2,
    float* __restrict__ outf, float* __restrict__ outf2,
    u16* __restrict__ outb, int NT) {
  __shared__ u16 lds[4 * 16384];  // 128 KB
  const int tid = threadIdx.x;
  const int wid = tid >> 6, lane = tid & 63;
  const int wm = wid >> 2, wn = wid & 3;  // 2 x 4 waves; per-wave out 128x64
  int head = 0, row0, colb;
  if (EPI == 3) {
    head = ((int)blockIdx.x >> 1) & 1;
    colb = ((int)blockIdx.x & 1) * 256;
    row0 = ((int)blockIdx.x >> 2) * 256;
  } else {
    row0 = ((int)blockIdx.x >> 1) * 256;
    colb = ((int)blockIdx.x & 1) * 256;
  }
  const u16* Bsrc = (EPI == 3) ? (head ? W2 : W1) : nullptr;

  f32x4 acc[8][4];
  const f32x4 z = {0.f, 0.f, 0.f, 0.f};
#pragma unroll
  for (int i = 0; i < 8; ++i)
#pragma unroll
    for (int j = 0; j < 4; ++j) acc[i][j] = z;

  const int lx = lane & 7, ly = lane >> 3;
  const int schunk = lx ^ ly;  // pre-swizzled global 16B-chunk for staging

  auto stage = [&](int t, int isB, int h) {
    u16* tile = lds + (size_t)(((t & 1) << 1) + isB) * 16384;
    const u16* G;
    if (EPI == 3) G = isB ? Bsrc : A1;
    else G = (t < 8) ? (isB ? W1 : A1) : (isB ? W2 : A2);
    const int kofs = ((t & 7) * 64) + schunk * 8;
    const int r0 = isB ? colb : row0;
#pragma unroll
    for (int q = 0; q < 2; ++q) {
      const int srw = q * 64 + wid * 8;
      const int r_w = ((srw >> 4) << 5) + h * 16 + (srw & 15);  // wave-uniform
      int rg = r0 + r_w + ly;
      if (!isB && rg > N_NODES - 1) rg = N_NODES - 1;
      const u16* g = G + (size_t)rg * 512 + kofs;
      __builtin_amdgcn_global_load_lds(
          (const __attribute__((address_space(1))) void*)g,
          (__attribute__((address_space(3))) void*)(tile + r_w * 64), 16, 0, 0);
    }
  };

  auto rdA = [&](const u16* T_, int ig, int kk) -> bf16x8 {
    const int r = (wm * 8 + ig) * 16 + (lane & 15);
    const int off = ((kk * 4 + (lane >> 4)) ^ (lane & 7)) * 8;
    return *(const bf16x8*)(T_ + r * 64 + off);
  };
  auto rdB = [&](const u16* T_, int jg, int kk) -> bf16x8 {
    const int r = (wn * 4 + jg) * 16 + (lane & 15);
    const int off = ((kk * 4 + (lane >> 4)) ^ (lane & 7)) * 8;
    return *(const bf16x8*)(T_ + r * 64 + off);
  };

  // prologue: tile 0, issue order A0, B0, A1, B1
  stage(0, 0, 0); stage(0, 1, 0); stage(0, 0, 1); stage(0, 1, 1);

  for (int t = 0; t < NT; ++t) {
    const u16* At = lds + (size_t)((t & 1) << 1) * 16384;
    const u16* Bt = At + 16384;
    const bool more = (t + 1 < NT);
    bf16x8 aF[4][2], bF[2][2];

    // ---- phase 1: quadrant (ih=0, jh=0); needs A-half0, B-half0 ----
    asm volatile("s_waitcnt vmcnt(4)" ::: "memory");
    __builtin_amdgcn_s_barrier();
    asm volatile("" ::: "memory");
    if (more) stage(t + 1, 0, 0);
#pragma unroll
    for (int ip = 0; ip < 4; ++ip)
#pragma unroll
      for (int kk = 0; kk < 2; ++kk) aF[ip][kk] = rdA(At, 2 * ip, kk);
#pragma unroll
    for (int jp = 0; jp < 2; ++jp)
#pragma unroll
      for (int kk = 0; kk < 2; ++kk) bF[jp][kk] = rdB(Bt, 2 * jp, kk);
    __builtin_amdgcn_s_setprio(1);
#pragma unroll
    for (int ip = 0; ip < 4; ++ip)
#pragma unroll
      for (int jp = 0; jp < 2; ++jp)
#pragma unroll
        for (int kk = 0; kk < 2; ++kk)
          acc[2 * ip][2 * jp] = MFMA(aF[ip][kk], bF[jp][kk], acc[2 * ip][2 * jp], 0, 0, 0);
    __builtin_amdgcn_s_setprio(0);

    // ---- phase 2: quadrant (0,1); needs B-half1 ----
    if (more) { asm volatile("s_waitcnt vmcnt(2)" ::: "memory"); }
    else      { asm volatile("s_waitcnt vmcnt(0)" ::: "memory"); }
    __builtin_amdgcn_s_barrier();
    asm volatile("" ::: "memory");
    if (more) stage(t + 1, 1, 0);
#pragma unroll
    for (int jp = 0; jp < 2; ++jp)
#pragma unroll
      for (int kk = 0; kk < 2; ++kk) bF[jp][kk] = rdB(Bt, 2 * jp + 1, kk);
    __builtin_amdgcn_s_setprio(1);
#pragma unroll
    for (int ip = 0; ip < 4; ++ip)
#pragma unroll
      for (int jp = 0; jp < 2; ++jp)
#pragma unroll
        for (int kk = 0; kk < 2; ++kk)
          acc[2 * ip][2 * jp + 1] = MFMA(aF[ip][kk], bF[jp][kk], acc[2 * ip][2 * jp + 1], 0, 0, 0);
    __builtin_amdgcn_s_setprio(0);

    // ---- phase 3: quadrant (1,1); needs A-half1 (ready per ph2 wait) ----
    if (more) stage(t + 1, 0, 1);
#pragma unroll
    for (int ip = 0; ip < 4; ++ip)
#pragma unroll
      for (int kk = 0; kk < 2; ++kk) aF[ip][kk] = rdA(At, 2 * ip + 1, kk);
    __builtin_amdgcn_s_setprio(1);
#pragma unroll
    for (int ip = 0; ip < 4; ++ip)
#pragma unroll
      for (int jp = 0; jp < 2; ++jp)
#pragma unroll
        for (int kk = 0; kk < 2; ++kk)
          acc[2 * ip + 1][2 * jp + 1] = MFMA(aF[ip][kk], bF[jp][kk], acc[2 * ip + 1][2 * jp + 1], 0, 0, 0);
    __builtin_amdgcn_s_setprio(0);

    // ---- phase 4: quadrant (1,0); B-half0 re-read ----
    if (more) stage(t + 1, 1, 1);
#pragma unroll
    for (int jp = 0; jp < 2; ++jp)
#pragma unroll
      for (int kk = 0; kk < 2; ++kk) bF[jp][kk] = rdB(Bt, 2 * jp, kk);
    __builtin_amdgcn_s_setprio(1);
#pragma unroll
    for (int ip = 0; ip < 4; ++ip)
#pragma unroll
      for (int jp = 0; jp < 2; ++jp)
#pragma unroll
        for (int kk = 0; kk < 2; ++kk)
          acc[2 * ip + 1][2 * jp] = MFMA(aF[ip][kk], bF[jp][kk], acc[2 * ip + 1][2 * jp], 0, 0, 0);
    __builtin_amdgcn_s_setprio(0);
  }

  // epilogue: C row = row0 + (wm*8+ig)*16 + (lane>>4)*4 + r ; col = colb + (wn*4+jg)*16 + (lane&15)
  const float* bs = (EPI == 3 && head) ? bias2 : bias;
  float* of = (EPI == 3 && head) ? outf2 : outf;
#pragma unroll
  for (int jg = 0; jg < 4; ++jg) {
    int col = colb + (wn * 4 + jg) * 16 + (lane & 15);
    float bb = bs[col];
#pragma unroll
    for (int ig = 0; ig < 8; ++ig) {
      int rbase = row0 + (wm * 8 + ig) * 16 + (lane >> 4) * 4;
      f32x4 v = acc[ig][jg];
#pragma unroll
      for (int r = 0; r < 4; ++r) {
        int row = rbase + r;
        if (row < N_NODES) {
          float f = v[r] + bb;
          if (EPI == 0) {
            f = fmaxf(f, 0.f);
            outb[(size_t)row * DIM + col] = f2bf(f);
          } else if (EPI == 1) {
            outf[(size_t)row * DIM + col] = f;
            outb[(size_t)row * DIM + col] = f2bf(f);
          } else {
            of[(size_t)row * DIM + col] = fmaxf(f, 0.f);
          }
        }
      }
    }
  }
}

// ---------------- launch ----------------
extern "C" void kernel_launch(void* const* d_in, const int* in_sizes, int n_in,
                              void* d_out, int out_size, void* d_ws, size_t ws_size,
                              hipStream_t stream) {
  (void)in_sizes; (void)n_in; (void)out_size; (void)ws_size;
  const float* x   = (const float*)d_in[0];
  const int*   ei  = (const int*)d_in[1];
  const float* Wl0 = (const float*)d_in[2];
  const float* bl0 = (const float*)d_in[3];
  const float* Wr0 = (const float*)d_in[4];
  const float* Wl1 = (const float*)d_in[5];
  const float* bl1 = (const float*)d_in[6];
  const float* Wr1 = (const float*)d_in[7];
  const float* Wv  = (const float*)d_in[8];
  const float* bv  = (const float*)d_in[9];
  const float* Wt  = (const float*)d_in[10];
  const float* bt  = (const float*)d_in[11];
  const int* srcI = ei;
  const int* dstI = ei + N_EDGES;

  float* out_h = (float*)d_out;
  float* out_v = out_h + (size_t)N_NODES * DIM;
  float* out_t = out_v + (size_t)N_NODES * DIM;
  u16* meanb  = (u16*)out_v;  // scratch: bf16 mean buffer (consumed before final write)
  u16* hrelub = (u16*)out_t;  // scratch: bf16 relu(h) buffer

  uint8_t* p = (uint8_t*)d_ws;
  auto carve = [&](size_t bytes) -> uint8_t* {
    uint8_t* r = p; p += (bytes + 1023) & ~(size_t)1023; return r;
  };
  int*   deg  = (int*)carve((size_t)N_NODES * 4);
  int*   offs = (int*)carve((size_t)(N_NODES + 1) * 4);
  int*   pos  = (int*)carve((size_t)N_NODES * 4);
  float* invd = (float*)carve((size_t)N_NODES * 4);
  int*   srcs = (int*)carve((size_t)N_EDGES * 4);
  u16* Wl0b = (u16*)carve(512 * 512 * 2);
  u16* Wr0b = (u16*)carve(512 * 512 * 2);
  u16* Wl1b = (u16*)carve(512 * 512 * 2);
  u16* Wr1b = (u16*)carve(512 * 512 * 2);
  u16* Wvb  = (u16*)carve(512 * 512 * 2);
  u16* Wtb  = (u16*)carve(512 * 512 * 2);
  u16* xb   = (u16*)carve((size_t)N_NODES * DIM * 2);  // x bf16, later h bf16

  const int EB = (N_EDGES + 255) / 256;

  hipMemsetAsync(deg, 0, (size_t)N_NODES * 4, stream);

  // fused: cvt_x + hist + 6x weight transpose
  k_prep<<<12500, 256, 0, stream>>>(x, xb, dstI, deg,
                                    Wl0, Wr0, Wl1, Wr1, Wv, Wt,
                                    Wl0b, Wr0b, Wl1b, Wr1b, Wvb, Wtb);
  k_scan<<<1, 1024, 0, stream>>>(deg, offs, pos, invd);
  k_scatter<<<EB, 256, 0, stream>>>(srcI, dstI, pos, srcs);

  const int GB = 392;  // 196 row-blocks x 2 col-blocks

  // layer 0: mean-agg(xb) -> meanb ; h0 = relu(mean@Wl0 + x@Wr0 + bl0) -> hrelub (bf16)
  k_agg_bf16<<<12500, 256, 0, stream>>>(xb, offs, srcs, invd, meanb);
  k_gemm8<0><<<GB, 512, 0, stream>>>(meanb, Wl0b, xb, Wr0b, bl0, nullptr,
                                     nullptr, nullptr, hrelub, 16);

  // layer 1: mean-agg(hrelub) -> meanb ; h = mean@Wl1 + h0@Wr1 + bl1 -> out_h (f32) + xb (bf16)
  k_agg_bf16<<<12500, 256, 0, stream>>>(hrelub, offs, srcs, invd, meanb);
  k_gemm8<1><<<GB, 512, 0, stream>>>(meanb, Wl1b, hrelub, Wr1b, bl1, nullptr,
                                     out_h, nullptr, xb, 16);

  // fused heads: relu(h@Wv + bv) -> out_v ; relu(h@Wt + bt) -> out_t
  k_gemm8<3><<<784, 512, 0, stream>>>(xb, Wvb, nullptr, Wtb, bv, bt,
                                      out_v, out_t, nullptr, 8);
}

// Round 2
// 650.850 us; speedup vs baseline: 1.0386x; 1.0270x over previous
//
#include <hip/hip_runtime.h>
#include <hip/hip_bf16.h>
#include <stdint.h>

#define N_NODES 50000
#define N_EDGES 500000
#define DIM 512

typedef unsigned short u16;
typedef unsigned int u32;
typedef __bf16 bf16x8 __attribute__((ext_vector_type(8)));
typedef float f32x4 __attribute__((ext_vector_type(4)));

static __device__ __forceinline__ u16 f2bf(float f) {
  union { __bf16 b; u16 u; } cv; cv.b = (__bf16)f; return cv.u;
}
static __device__ __forceinline__ float bf2f(u16 u) {
  union { u16 u; __bf16 b; } cv; cv.u = u; return (float)cv.b;
}

// ---------------- CSR build ----------------
__global__ __launch_bounds__(1024) void k_scan(const int* __restrict__ deg,
                                               int* __restrict__ offs,
                                               int* __restrict__ pos,
                                               float* __restrict__ invd) {
  __shared__ int sums[1024];
  const int tid = threadIdx.x;
  const int CH = 49;  // 1024*49 = 50176 >= 50000
  int lo = tid * CH;
  int hi = lo + CH; if (hi > N_NODES) hi = N_NODES;
  if (lo > N_NODES) lo = N_NODES;
  int s = 0;
  for (int i = lo; i < hi; ++i) s += deg[i];
  sums[tid] = s;
  __syncthreads();
  for (int off = 1; off < 1024; off <<= 1) {
    int t = (tid >= off) ? sums[tid - off] : 0;
    __syncthreads();
    sums[tid] += t;
    __syncthreads();
  }
  int run = sums[tid] - s;  // exclusive prefix of this chunk
  for (int i = lo; i < hi; ++i) {
    int d = deg[i];
    offs[i] = run; pos[i] = run;
    invd[i] = 1.0f / (float)((d > 1) ? d : 1);
    run += d;
  }
  if (tid == 1023) offs[N_NODES] = run;
}

// srcs stores src*DIM (u16-element offset) so agg skips the multiply
__global__ void k_scatter(const int* __restrict__ src, const int* __restrict__ dst,
                          int* __restrict__ pos, int* __restrict__ srcs) {
  int e = blockIdx.x * blockDim.x + threadIdx.x;
  if (e < N_EDGES) {
    int p = atomicAdd(&pos[dst[e]], 1);
    srcs[p] = src[e] * DIM;
  }
}

// ---------------- fused prep: cvt_x + edge histogram + 6x weight transpose ----
__global__ __launch_bounds__(256) void k_prep(
    const float* __restrict__ x, u16* __restrict__ xb,
    const int* __restrict__ dst, int* __restrict__ deg,
    const float* __restrict__ Wa, const float* __restrict__ Wb,
    const float* __restrict__ Wc, const float* __restrict__ Wd,
    const float* __restrict__ We, const float* __restrict__ Wf,
    u16* __restrict__ Oa, u16* __restrict__ Ob, u16* __restrict__ Oc,
    u16* __restrict__ Od, u16* __restrict__ Oe, u16* __restrict__ Of) {
  __shared__ u16 tbuf[64][66];
  const int t = blockIdx.x * 256 + threadIdx.x;

  // --- cvt_x: 8 floats -> 8 bf16 per thread ---
  const float4* p = (const float4*)(x + (size_t)t * 8);
  float4 a = p[0], b = p[1];
  uint4 o;
  o.x = (u32)f2bf(a.x) | ((u32)f2bf(a.y) << 16);
  o.y = (u32)f2bf(a.z) | ((u32)f2bf(a.w) << 16);
  o.z = (u32)f2bf(b.x) | ((u32)f2bf(b.y) << 16);
  o.w = (u32)f2bf(b.z) | ((u32)f2bf(b.w) << 16);
  *(uint4*)(xb + (size_t)t * 8) = o;

  // --- edge degree histogram ---
  if (t < N_EDGES) atomicAdd(&deg[dst[t]], 1);

  // --- weight transpose (last 384 blocks) ---
  const int wb = (int)blockIdx.x - (12500 - 384);
  if (wb >= 0) {
    const float* W; u16* O;
    switch (wb / 64) {
      case 0: W = Wa; O = Oa; break;
      case 1: W = Wb; O = Ob; break;
      case 2: W = Wc; O = Oc; break;
      case 3: W = Wd; O = Od; break;
      case 4: W = We; O = Oe; break;
      default: W = Wf; O = Of; break;
    }
    const int rem = wb & 63;
    const int k0 = (rem & 7) * 64, n0 = (rem >> 3) * 64;
    const int lr = threadIdx.x & 63, wr = threadIdx.x >> 6;
#pragma unroll
    for (int rr = 0; rr < 16; ++rr) {
      int k = k0 + wr * 16 + rr;
      tbuf[lr][wr * 16 + rr] = f2bf(W[(size_t)k * 512 + n0 + lr]);
    }
    __syncthreads();
#pragma unroll
    for (int rr = 0; rr < 16; ++rr) {
      int n = n0 + wr * 16 + rr;
      O[(size_t)n * 512 + k0 + lr] = tbuf[wr * 16 + rr][lr];
    }
  }
}

// ---------------- aggregation: one wave per node, bf16 gather ----------------
#define ACC1(q)                                              \
  acc[0] += bf2f((q).x & 0xffff); acc[1] += bf2f((u16)((q).x >> 16)); \
  acc[2] += bf2f((q).y & 0xffff); acc[3] += bf2f((u16)((q).y >> 16)); \
  acc[4] += bf2f((q).z & 0xffff); acc[5] += bf2f((u16)((q).z >> 16)); \
  acc[6] += bf2f((q).w & 0xffff); acc[7] += bf2f((u16)((q).w >> 16));

__global__ __launch_bounds__(256) void k_agg_bf16(
    const u16* __restrict__ hb, const int* __restrict__ offs,
    const int* __restrict__ srcs, const float* __restrict__ invd,
    u16* __restrict__ outb) {
  int node = blockIdx.x * 4 + (threadIdx.x >> 6);
  int lane = threadIdx.x & 63;
  if (node >= N_NODES) return;
  int s0 = offs[node], s1 = offs[node + 1];
  float acc[8] = {0, 0, 0, 0, 0, 0, 0, 0};
  const u16* hl = hb + lane * 8;
  int i = s0;
  for (; i + 4 <= s1; i += 4) {
    int sa = srcs[i], sb = srcs[i + 1], sc = srcs[i + 2], sd = srcs[i + 3];
    uint4 qa = *(const uint4*)(hl + sa);
    uint4 qb = *(const uint4*)(hl + sb);
    uint4 qc = *(const uint4*)(hl + sc);
    uint4 qd = *(const uint4*)(hl + sd);
    ACC1(qa) ACC1(qb) ACC1(qc) ACC1(qd)
  }
  if (i + 2 <= s1) {
    int sa = srcs[i], sb = srcs[i + 1];
    uint4 qa = *(const uint4*)(hl + sa);
    uint4 qb = *(const uint4*)(hl + sb);
    ACC1(qa) ACC1(qb)
    i += 2;
  }
  if (i < s1) {
    int sa = srcs[i];
    uint4 qa = *(const uint4*)(hl + sa);
    ACC1(qa)
  }
  float iv = invd[node];
  uint4 o;
  o.x = (u32)f2bf(acc[0] * iv) | ((u32)f2bf(acc[1] * iv) << 16);
  o.y = (u32)f2bf(acc[2] * iv) | ((u32)f2bf(acc[3] * iv) << 16);
  o.z = (u32)f2bf(acc[4] * iv) | ((u32)f2bf(acc[5] * iv) << 16);
  o.w = (u32)f2bf(acc[6] * iv) | ((u32)f2bf(acc[7] * iv) << 16);
  *(uint4*)(outb + (size_t)node * DIM + lane * 8) = o;
}

// ---------------- GEMM: 112x512 tile, BK=64, 8 waves, 4-phase pipeline --------
// C[M,512] = A1@W1t (+ A2@W2t) + bias.  A row-major [M,512] bf16;
// W pre-transposed [Nout=512][K=512] bf16.  BN=512 => A read ONCE.
// Grid: M/112 = 448 exact row tiles (x2 for dual-head EPI 3).
// LDS 156KB: 2 buffers x (A 112x64 + B 512x64) bf16, XOR-chunk swizzle
// (16B chunk slot = c ^ (row&7), row stride 128B = 8 chunks).
// 8 waves, 1x8: wave w owns cols [w*64, w*64+63]; acc[7][4] f32x4.
// Per-tile issue order (per wave, 10 global_load_lds):
//   A-h0(1), B-jh0(4), B-jh1(4), A-h1(1; waves 6,7 duplicate rows 96..111)
// Waits: ph1 vmcnt(5) -> A0+Bjh0 landed; ph2 vmcnt(1|0) -> all of tile t
// landed (covers Bjh1 + A1; ph2 barrier makes cross-wave staging visible
// before ph3 reads A-h1).
// EPI: 0 = relu -> bf16   1 = f32 + bf16 copy (no relu)
// EPI 3 = fused dual-head: head = bx&1 selects (W2,bias2,outf2); relu -> f32.
#define MFMA __builtin_amdgcn_mfma_f32_16x16x32_bf16
#define BUFU 39936  // u16 per buffer: A 7168 + B 32768

template <int EPI>
__global__ __launch_bounds__(512, 2) void k_gemm112(
    const u16* __restrict__ A1, const u16* __restrict__ W1,
    const u16* __restrict__ A2, const u16* __restrict__ W2,
    const float* __restrict__ bias, const float* __restrict__ bias2,
    float* __restrict__ outf, float* __restrict__ outf2,
    u16* __restrict__ outb, int NT) {
  __shared__ u16 lds[2 * BUFU];  // 156 KB
  const int tid = threadIdx.x;
  const int wid = tid >> 6, lane = tid & 63;
  int head = 0, row0;
  if (EPI == 3) {
    head = (int)blockIdx.x & 1;
    row0 = ((int)blockIdx.x >> 1) * 112;
  } else {
    row0 = (int)blockIdx.x * 112;
  }
  const u16* BW = (EPI == 3) ? (head ? W2 : W1) : nullptr;

  f32x4 acc[7][4];
  const f32x4 z = {0.f, 0.f, 0.f, 0.f};
#pragma unroll
  for (int i = 0; i < 7; ++i)
#pragma unroll
    for (int j = 0; j < 4; ++j) acc[i][j] = z;

  const int ly = lane >> 3;
  const int schunk = (lane & 7) ^ ly;  // pre-swizzled global 16B-chunk

  // A tile rows 0..111 (+ ly per lane); half h: rows h*64 + w*8
  auto stageA = [&](int t, int h) {
    u16* tile = lds + (t & 1) * BUFU;
    const u16* G = (EPI == 3) ? A1 : ((t < 8) ? A1 : A2);
    int w = wid;
    if (h && w >= 6) w -= 2;  // duplicate rows 96..111 (same src+dest, benign)
    const int rb = h * 64 + w * 8;
    int rg = row0 + rb + ly;
    if (rg > N_NODES - 1) rg = N_NODES - 1;
    const u16* g = G + (size_t)rg * 512 + (t & 7) * 64 + schunk * 8;
    __builtin_amdgcn_global_load_lds(
        (const __attribute__((address_space(1))) void*)g,
        (__attribute__((address_space(3))) void*)(tile + rb * 64), 16, 0, 0);
  };

  // B tile rows 0..511; jh half = rows with (r&32)==jh*32
  auto stageB = [&](int t, int jh) {
    u16* tile = lds + (t & 1) * BUFU + 7168;
    const u16* G = (EPI == 3) ? BW : ((t < 8) ? W1 : W2);
    const int kofs = (t & 7) * 64 + schunk * 8;
#pragma unroll
    for (int u = 0; u < 4; ++u) {
      const int rb = u * 128 + (wid >> 2) * 64 + (wid & 3) * 8 + jh * 32;
      const u16* g = G + (size_t)(rb + ly) * 512 + kofs;
      __builtin_amdgcn_global_load_lds(
          (const __attribute__((address_space(1))) void*)g,
          (__attribute__((address_space(3))) void*)(tile + rb * 64), 16, 0, 0);
    }
  };

  auto rdA = [&](const u16* T_, int ig, int kk) -> bf16x8 {
    const int r = ig * 16 + (lane & 15);
    const int off = ((kk * 4 + (lane >> 4)) ^ (lane & 7)) * 8;
    return *(const bf16x8*)(T_ + r * 64 + off);
  };
  auto rdB = [&](const u16* T_, int jg, int kk) -> bf16x8 {
    const int r = wid * 64 + jg * 16 + (lane & 15);
    const int off = ((kk * 4 + (lane >> 4)) ^ (lane & 7)) * 8;
    return *(const bf16x8*)(T_ + r * 64 + off);
  };

  // prologue: tile 0, order A0, Bjh0, Bjh1, A1 (10 loads/wave)
  stageA(0, 0); stageB(0, 0); stageB(0, 1); stageA(0, 1);

  for (int t = 0; t < NT; ++t) {
    const u16* At = lds + (t & 1) * BUFU;
    const u16* Bt = At + 7168;
    const bool more = (t + 1 < NT);
    bf16x8 aF[4][2], bF[2][2];

    // ---- phase 1: (ig 0-3, jg 0-1); needs A-h0 + B-jh0 ----
    asm volatile("s_waitcnt vmcnt(5)" ::: "memory");
    __builtin_amdgcn_s_barrier();
    asm volatile("" ::: "memory");
    if (more) stageA(t + 1, 0);
#pragma unroll
    for (int ip = 0; ip < 4; ++ip)
#pragma unroll
      for (int kk = 0; kk < 2; ++kk) aF[ip][kk] = rdA(At, ip, kk);
#pragma unroll
    for (int jp = 0; jp < 2; ++jp)
#pragma unroll
      for (int kk = 0; kk < 2; ++kk) bF[jp][kk] = rdB(Bt, jp, kk);
    __builtin_amdgcn_s_setprio(1);
#pragma unroll
    for (int ip = 0; ip < 4; ++ip)
#pragma unroll
      for (int jp = 0; jp < 2; ++jp)
#pragma unroll
        for (int kk = 0; kk < 2; ++kk)
          acc[ip][jp] = MFMA(aF[ip][kk], bF[jp][kk], acc[ip][jp], 0, 0, 0);
    __builtin_amdgcn_s_setprio(0);

    // ---- phase 2: (ig 0-3, jg 2-3); needs B-jh1 (+A-h1 rides along) ----
    if (more) { asm volatile("s_waitcnt vmcnt(1)" ::: "memory"); }
    else      { asm volatile("s_waitcnt vmcnt(0)" ::: "memory"); }
    __builtin_amdgcn_s_barrier();
    asm volatile("" ::: "memory");
    if (more) stageB(t + 1, 0);
#pragma unroll
    for (int jp = 0; jp < 2; ++jp)
#pragma unroll
      for (int kk = 0; kk < 2; ++kk) bF[jp][kk] = rdB(Bt, 2 + jp, kk);
    __builtin_amdgcn_s_setprio(1);
#pragma unroll
    for (int ip = 0; ip < 4; ++ip)
#pragma unroll
      for (int jp = 0; jp < 2; ++jp)
#pragma unroll
        for (int kk = 0; kk < 2; ++kk)
          acc[ip][2 + jp] = MFMA(aF[ip][kk], bF[jp][kk], acc[ip][2 + jp], 0, 0, 0);
    __builtin_amdgcn_s_setprio(0);

    // ---- phase 3: (ig 4-6, jg 2-3); A-h1 landed per ph2 wait+barrier ----
    if (more) stageB(t + 1, 1);
#pragma unroll
    for (int ip = 0; ip < 3; ++ip)
#pragma unroll
      for (int kk = 0; kk < 2; ++kk) aF[ip][kk] = rdA(At, 4 + ip, kk);
    __builtin_amdgcn_s_setprio(1);
#pragma unroll
    for (int ip = 0; ip < 3; ++ip)
#pragma unroll
      for (int jp = 0; jp < 2; ++jp)
#pragma unroll
        for (int kk = 0; kk < 2; ++kk)
          acc[4 + ip][2 + jp] = MFMA(aF[ip][kk], bF[jp][kk], acc[4 + ip][2 + jp], 0, 0, 0);
    __builtin_amdgcn_s_setprio(0);

    // ---- phase 4: (ig 4-6, jg 0-1); B-jh0 re-read ----
    if (more) stageA(t + 1, 1);
#pragma unroll
    for (int jp = 0; jp < 2; ++jp)
#pragma unroll
      for (int kk = 0; kk < 2; ++kk) bF[jp][kk] = rdB(Bt, jp, kk);
    __builtin_amdgcn_s_setprio(1);
#pragma unroll
    for (int ip = 0; ip < 3; ++ip)
#pragma unroll
      for (int jp = 0; jp < 2; ++jp)
#pragma unroll
        for (int kk = 0; kk < 2; ++kk)
          acc[4 + ip][jp] = MFMA(aF[ip][kk], bF[jp][kk], acc[4 + ip][jp], 0, 0, 0);
    __builtin_amdgcn_s_setprio(0);
  }

  // epilogue: row = row0 + ig*16 + (lane>>4)*4 + r ; col = wid*64 + jg*16 + (lane&15)
  const float* bs = (EPI == 3 && head) ? bias2 : bias;
  float* of = (EPI == 3 && head) ? outf2 : outf;
#pragma unroll
  for (int jg = 0; jg < 4; ++jg) {
    int col = wid * 64 + jg * 16 + (lane & 15);
    float bb = bs[col];
#pragma unroll
    for (int ig = 0; ig < 7; ++ig) {
      int rbase = row0 + ig * 16 + (lane >> 4) * 4;
      f32x4 v = acc[ig][jg];
#pragma unroll
      for (int r = 0; r < 4; ++r) {
        int row = rbase + r;
        if (row < N_NODES) {
          float f = v[r] + bb;
          if (EPI == 0) {
            f = fmaxf(f, 0.f);
            outb[(size_t)row * DIM + col] = f2bf(f);
          } else if (EPI == 1) {
            outf[(size_t)row * DIM + col] = f;
            outb[(size_t)row * DIM + col] = f2bf(f);
          } else {
            of[(size_t)row * DIM + col] = fmaxf(f, 0.f);
          }
        }
      }
    }
  }
}

// ---------------- launch ----------------
extern "C" void kernel_launch(void* const* d_in, const int* in_sizes, int n_in,
                              void* d_out, int out_size, void* d_ws, size_t ws_size,
                              hipStream_t stream) {
  (void)in_sizes; (void)n_in; (void)out_size; (void)ws_size;
  const float* x   = (const float*)d_in[0];
  const int*   ei  = (const int*)d_in[1];
  const float* Wl0 = (const float*)d_in[2];
  const float* bl0 = (const float*)d_in[3];
  const float* Wr0 = (const float*)d_in[4];
  const float* Wl1 = (const float*)d_in[5];
  const float* bl1 = (const float*)d_in[6];
  const float* Wr1 = (const float*)d_in[7];
  const float* Wv  = (const float*)d_in[8];
  const float* bv  = (const float*)d_in[9];
  const float* Wt  = (const float*)d_in[10];
  const float* bt  = (const float*)d_in[11];
  const int* srcI = ei;
  const int* dstI = ei + N_EDGES;

  float* out_h = (float*)d_out;
  float* out_v = out_h + (size_t)N_NODES * DIM;
  float* out_t = out_v + (size_t)N_NODES * DIM;
  u16* meanb  = (u16*)out_v;  // scratch: bf16 mean buffer (consumed before final write)
  u16* hrelub = (u16*)out_t;  // scratch: bf16 relu(h) buffer

  uint8_t* p = (uint8_t*)d_ws;
  auto carve = [&](size_t bytes) -> uint8_t* {
    uint8_t* r = p; p += (bytes + 1023) & ~(size_t)1023; return r;
  };
  int*   deg  = (int*)carve((size_t)N_NODES * 4);
  int*   offs = (int*)carve((size_t)(N_NODES + 1) * 4);
  int*   pos  = (int*)carve((size_t)N_NODES * 4);
  float* invd = (float*)carve((size_t)N_NODES * 4);
  int*   srcs = (int*)carve((size_t)N_EDGES * 4);
  u16* Wl0b = (u16*)carve(512 * 512 * 2);
  u16* Wr0b = (u16*)carve(512 * 512 * 2);
  u16* Wl1b = (u16*)carve(512 * 512 * 2);
  u16* Wr1b = (u16*)carve(512 * 512 * 2);
  u16* Wvb  = (u16*)carve(512 * 512 * 2);
  u16* Wtb  = (u16*)carve(512 * 512 * 2);
  u16* xb   = (u16*)carve((size_t)N_NODES * DIM * 2);  // x bf16, later h bf16

  const int EB = (N_EDGES + 255) / 256;

  hipMemsetAsync(deg, 0, (size_t)N_NODES * 4, stream);

  // fused: cvt_x + hist + 6x weight transpose
  k_prep<<<12500, 256, 0, stream>>>(x, xb, dstI, deg,
                                    Wl0, Wr0, Wl1, Wr1, Wv, Wt,
                                    Wl0b, Wr0b, Wl1b, Wr1b, Wvb, Wtb);
  k_scan<<<1, 1024, 0, stream>>>(deg, offs, pos, invd);
  k_scatter<<<EB, 256, 0, stream>>>(srcI, dstI, pos, srcs);

  const int GB = 448;  // 448 row tiles of 112 rows (448*112 = 50176)

  // layer 0: mean-agg(xb) -> meanb ; h0 = relu(mean@Wl0 + x@Wr0 + bl0) -> hrelub (bf16)
  k_agg_bf16<<<12500, 256, 0, stream>>>(xb, offs, srcs, invd, meanb);
  k_gemm112<0><<<GB, 512, 0, stream>>>(meanb, Wl0b, xb, Wr0b, bl0, nullptr,
                                       nullptr, nullptr, hrelub, 16);

  // layer 1: mean-agg(hrelub) -> meanb ; h = mean@Wl1 + h0@Wr1 + bl1 -> out_h (f32) + xb (bf16)
  k_agg_bf16<<<12500, 256, 0, stream>>>(hrelub, offs, srcs, invd, meanb);
  k_gemm112<1><<<GB, 512, 0, stream>>>(meanb, Wl1b, hrelub, Wr1b, bl1, nullptr,
                                       out_h, nullptr, xb, 16);

  // fused heads: relu(h@Wv + bv) -> out_v ; relu(h@Wt + bt) -> out_t
  k_gemm112<3><<<896, 512, 0, stream>>>(xb, Wvb, nullptr, Wtb, bv, bt,
                                        out_v, out_t, nullptr, 8);
}

// Round 3
// 648.662 us; speedup vs baseline: 1.0421x; 1.0034x over previous
//
#include <hip/hip_runtime.h>
#include <hip/hip_bf16.h>
#include <stdint.h>

#define N_NODES 50000
#define N_EDGES 500000
#define DIM 512

typedef unsigned short u16;
typedef unsigned int u32;
typedef __bf16 bf16x8 __attribute__((ext_vector_type(8)));
typedef float f32x4 __attribute__((ext_vector_type(4)));

static __device__ __forceinline__ u16 f2bf(float f) {
  union { __bf16 b; u16 u; } cv; cv.b = (__bf16)f; return cv.u;
}
static __device__ __forceinline__ float bf2f(u16 u) {
  union { u16 u; __bf16 b; } cv; cv.u = u; return (float)cv.b;
}

// ---------------- deg zero (replaces pathological hipMemsetAsync blit) -------
__global__ void k_zero(int4* __restrict__ deg4) {
  int t = blockIdx.x * 256 + threadIdx.x;
  if (t < 12500) deg4[t] = make_int4(0, 0, 0, 0);  // 12500*16B = 200000B exact
}

// ---------------- CSR build ----------------
__global__ __launch_bounds__(1024) void k_scan(const int* __restrict__ deg,
                                               int* __restrict__ offs,
                                               int* __restrict__ pos,
                                               float* __restrict__ invd) {
  __shared__ int sums[1024];
  const int tid = threadIdx.x;
  const int CH = 49;  // 1024*49 = 50176 >= 50000
  int lo = tid * CH;
  int hi = lo + CH; if (hi > N_NODES) hi = N_NODES;
  if (lo > N_NODES) lo = N_NODES;
  int s = 0;
  for (int i = lo; i < hi; ++i) s += deg[i];
  sums[tid] = s;
  __syncthreads();
  for (int off = 1; off < 1024; off <<= 1) {
    int t = (tid >= off) ? sums[tid - off] : 0;
    __syncthreads();
    sums[tid] += t;
    __syncthreads();
  }
  int run = sums[tid] - s;  // exclusive prefix of this chunk
  for (int i = lo; i < hi; ++i) {
    int d = deg[i];
    offs[i] = run; pos[i] = run;
    invd[i] = 1.0f / (float)((d > 1) ? d : 1);
    run += d;
  }
  if (tid == 1023) offs[N_NODES] = run;
}

// srcs stores src*DIM (u16-element offset) so agg skips the multiply
__global__ void k_scatter(const int* __restrict__ src, const int* __restrict__ dst,
                          int* __restrict__ pos, int* __restrict__ srcs) {
  int e = blockIdx.x * blockDim.x + threadIdx.x;
  if (e < N_EDGES) {
    int p = atomicAdd(&pos[dst[e]], 1);
    srcs[p] = src[e] * DIM;
  }
}

// ---------------- fused prep: cvt_x + edge histogram + 6x weight transpose ----
__global__ __launch_bounds__(256) void k_prep(
    const float* __restrict__ x, u16* __restrict__ xb,
    const int* __restrict__ dst, int* __restrict__ deg,
    const float* __restrict__ Wa, const float* __restrict__ Wb,
    const float* __restrict__ Wc, const float* __restrict__ Wd,
    const float* __restrict__ We, const float* __restrict__ Wf,
    u16* __restrict__ Oa, u16* __restrict__ Ob, u16* __restrict__ Oc,
    u16* __restrict__ Od, u16* __restrict__ Oe, u16* __restrict__ Of) {
  __shared__ u16 tbuf[64][66];
  const int t = blockIdx.x * 256 + threadIdx.x;

  // --- cvt_x: 8 floats -> 8 bf16 per thread ---
  const float4* p = (const float4*)(x + (size_t)t * 8);
  float4 a = p[0], b = p[1];
  uint4 o;
  o.x = (u32)f2bf(a.x) | ((u32)f2bf(a.y) << 16);
  o.y = (u32)f2bf(a.z) | ((u32)f2bf(a.w) << 16);
  o.z = (u32)f2bf(b.x) | ((u32)f2bf(b.y) << 16);
  o.w = (u32)f2bf(b.z) | ((u32)f2bf(b.w) << 16);
  *(uint4*)(xb + (size_t)t * 8) = o;

  // --- edge degree histogram ---
  if (t < N_EDGES) atomicAdd(&deg[dst[t]], 1);

  // --- weight transpose (last 384 blocks) ---
  const int wb = (int)blockIdx.x - (12500 - 384);
  if (wb >= 0) {
    const float* W; u16* O;
    switch (wb / 64) {
      case 0: W = Wa; O = Oa; break;
      case 1: W = Wb; O = Ob; break;
      case 2: W = Wc; O = Oc; break;
      case 3: W = Wd; O = Od; break;
      case 4: W = We; O = Oe; break;
      default: W = Wf; O = Of; break;
    }
    const int rem = wb & 63;
    const int k0 = (rem & 7) * 64, n0 = (rem >> 3) * 64;
    const int lr = threadIdx.x & 63, wr = threadIdx.x >> 6;
#pragma unroll
    for (int rr = 0; rr < 16; ++rr) {
      int k = k0 + wr * 16 + rr;
      tbuf[lr][wr * 16 + rr] = f2bf(W[(size_t)k * 512 + n0 + lr]);
    }
    __syncthreads();
#pragma unroll
    for (int rr = 0; rr < 16; ++rr) {
      int n = n0 + wr * 16 + rr;
      O[(size_t)n * 512 + k0 + lr] = tbuf[wr * 16 + rr][lr];
    }
  }
}

// ---------------- aggregation: one wave per node, bf16 gather ----------------
#define ACC1(q)                                              \
  acc[0] += bf2f((q).x & 0xffff); acc[1] += bf2f((u16)((q).x >> 16)); \
  acc[2] += bf2f((q).y & 0xffff); acc[3] += bf2f((u16)((q).y >> 16)); \
  acc[4] += bf2f((q).z & 0xffff); acc[5] += bf2f((u16)((q).z >> 16)); \
  acc[6] += bf2f((q).w & 0xffff); acc[7] += bf2f((u16)((q).w >> 16));

__global__ __launch_bounds__(256) void k_agg_bf16(
    const u16* __restrict__ hb, const int* __restrict__ offs,
    const int* __restrict__ srcs, const float* __restrict__ invd,
    u16* __restrict__ outb) {
  int node = blockIdx.x * 4 + (threadIdx.x >> 6);
  int lane = threadIdx.x & 63;
  if (node >= N_NODES) return;
  int s0 = offs[node], s1 = offs[node + 1];
  float acc[8] = {0, 0, 0, 0, 0, 0, 0, 0};
  const u16* hl = hb + lane * 8;
  int i = s0;
  for (; i + 4 <= s1; i += 4) {
    int sa = srcs[i], sb = srcs[i + 1], sc = srcs[i + 2], sd = srcs[i + 3];
    uint4 qa = *(const uint4*)(hl + sa);
    uint4 qb = *(const uint4*)(hl + sb);
    uint4 qc = *(const uint4*)(hl + sc);
    uint4 qd = *(const uint4*)(hl + sd);
    ACC1(qa) ACC1(qb) ACC1(qc) ACC1(qd)
  }
  if (i + 2 <= s1) {
    int sa = srcs[i], sb = srcs[i + 1];
    uint4 qa = *(const uint4*)(hl + sa);
    uint4 qb = *(const uint4*)(hl + sb);
    ACC1(qa) ACC1(qb)
    i += 2;
  }
  if (i < s1) {
    int sa = srcs[i];
    uint4 qa = *(const uint4*)(hl + sa);
    ACC1(qa)
  }
  float iv = invd[node];
  uint4 o;
  o.x = (u32)f2bf(acc[0] * iv) | ((u32)f2bf(acc[1] * iv) << 16);
  o.y = (u32)f2bf(acc[2] * iv) | ((u32)f2bf(acc[3] * iv) << 16);
  o.z = (u32)f2bf(acc[4] * iv) | ((u32)f2bf(acc[5] * iv) << 16);
  o.w = (u32)f2bf(acc[6] * iv) | ((u32)f2bf(acc[7] * iv) << 16);
  *(uint4*)(outb + (size_t)node * DIM + lane * 8) = o;
}

// ---------------- GEMM: 112x512 tile, BK=64, 8 waves, 4-phase pipeline --------
// C[M,512] = A1@W1t (+ A2@W2t) + bias.  A row-major [M,512] bf16;
// W pre-transposed [Nout=512][K=512] bf16.  BN=512 => A read ONCE.
// Grid: M/112 = 448 exact row tiles (x2 for dual-head EPI 3).
// LDS 156KB: 2 buffers x (A 112x64 + B 512x64) bf16, XOR-chunk swizzle.
// Per-tile issue order (per wave, 10 global_load_lds):
//   A-h0(1), B-jh0(4), B-jh1(4), A-h1(1; waves 6,7 duplicate rows 96..111)
// Waits: ph1 vmcnt(5); ph2 vmcnt(1|0).
// EPI: 0 = relu -> bf16   1 = f32 + bf16 copy (no relu)
// EPI 3 = fused dual-head: head = bx&1 selects (W2,bias2,outf2); relu -> f32.
#define MFMA __builtin_amdgcn_mfma_f32_16x16x32_bf16
#define BUFU 39936  // u16 per buffer: A 7168 + B 32768

template <int EPI>
__global__ __launch_bounds__(512, 2) void k_gemm112(
    const u16* __restrict__ A1, const u16* __restrict__ W1,
    const u16* __restrict__ A2, const u16* __restrict__ W2,
    const float* __restrict__ bias, const float* __restrict__ bias2,
    float* __restrict__ outf, float* __restrict__ outf2,
    u16* __restrict__ outb, int NT) {
  __shared__ u16 lds[2 * BUFU];  // 156 KB
  const int tid = threadIdx.x;
  const int wid = tid >> 6, lane = tid & 63;
  int head = 0, row0;
  if (EPI == 3) {
    head = (int)blockIdx.x & 1;
    row0 = ((int)blockIdx.x >> 1) * 112;
  } else {
    row0 = (int)blockIdx.x * 112;
  }
  const u16* BW = (EPI == 3) ? (head ? W2 : W1) : nullptr;

  f32x4 acc[7][4];
  const f32x4 z = {0.f, 0.f, 0.f, 0.f};
#pragma unroll
  for (int i = 0; i < 7; ++i)
#pragma unroll
    for (int j = 0; j < 4; ++j) acc[i][j] = z;

  const int ly = lane >> 3;
  const int schunk = (lane & 7) ^ ly;  // pre-swizzled global 16B-chunk

  // A tile rows 0..111 (+ ly per lane); half h: rows h*64 + w*8
  auto stageA = [&](int t, int h) {
    u16* tile = lds + (t & 1) * BUFU;
    const u16* G = (EPI == 3) ? A1 : ((t < 8) ? A1 : A2);
    int w = wid;
    if (h && w >= 6) w -= 2;  // duplicate rows 96..111 (same src+dest, benign)
    const int rb = h * 64 + w * 8;
    int rg = row0 + rb + ly;
    if (rg > N_NODES - 1) rg = N_NODES - 1;
    const u16* g = G + (size_t)rg * 512 + (t & 7) * 64 + schunk * 8;
    __builtin_amdgcn_global_load_lds(
        (const __attribute__((address_space(1))) void*)g,
        (__attribute__((address_space(3))) void*)(tile + rb * 64), 16, 0, 0);
  };

  // B tile rows 0..511; jh half = rows with (r&32)==jh*32
  auto stageB = [&](int t, int jh) {
    u16* tile = lds + (t & 1) * BUFU + 7168;
    const u16* G = (EPI == 3) ? BW : ((t < 8) ? W1 : W2);
    const int kofs = (t & 7) * 64 + schunk * 8;
#pragma unroll
    for (int u = 0; u < 4; ++u) {
      const int rb = u * 128 + (wid >> 2) * 64 + (wid & 3) * 8 + jh * 32;
      const u16* g = G + (size_t)(rb + ly) * 512 + kofs;
      __builtin_amdgcn_global_load_lds(
          (const __attribute__((address_space(1))) void*)g,
          (__attribute__((address_space(3))) void*)(tile + rb * 64), 16, 0, 0);
    }
  };

  auto rdA = [&](const u16* T_, int ig, int kk) -> bf16x8 {
    const int r = ig * 16 + (lane & 15);
    const int off = ((kk * 4 + (lane >> 4)) ^ (lane & 7)) * 8;
    return *(const bf16x8*)(T_ + r * 64 + off);
  };
  auto rdB = [&](const u16* T_, int jg, int kk) -> bf16x8 {
    const int r = wid * 64 + jg * 16 + (lane & 15);
    const int off = ((kk * 4 + (lane >> 4)) ^ (lane & 7)) * 8;
    return *(const bf16x8*)(T_ + r * 64 + off);
  };

  // prologue: tile 0, order A0, Bjh0, Bjh1, A1 (10 loads/wave)
  stageA(0, 0); stageB(0, 0); stageB(0, 1); stageA(0, 1);

  for (int t = 0; t < NT; ++t) {
    const u16* At = lds + (t & 1) * BUFU;
    const u16* Bt = At + 7168;
    const bool more = (t + 1 < NT);
    bf16x8 aF[4][2], bF[2][2];

    // ---- phase 1: (ig 0-3, jg 0-1); needs A-h0 + B-jh0 ----
    asm volatile("s_waitcnt vmcnt(5)" ::: "memory");
    __builtin_amdgcn_s_barrier();
    asm volatile("" ::: "memory");
    if (more) stageA(t + 1, 0);
#pragma unroll
    for (int ip = 0; ip < 4; ++ip)
#pragma unroll
      for (int kk = 0; kk < 2; ++kk) aF[ip][kk] = rdA(At, ip, kk);
#pragma unroll
    for (int jp = 0; jp < 2; ++jp)
#pragma unroll
      for (int kk = 0; kk < 2; ++kk) bF[jp][kk] = rdB(Bt, jp, kk);
    __builtin_amdgcn_s_setprio(1);
#pragma unroll
    for (int ip = 0; ip < 4; ++ip)
#pragma unroll
      for (int jp = 0; jp < 2; ++jp)
#pragma unroll
        for (int kk = 0; kk < 2; ++kk)
          acc[ip][jp] = MFMA(aF[ip][kk], bF[jp][kk], acc[ip][jp], 0, 0, 0);
    __builtin_amdgcn_s_setprio(0);

    // ---- phase 2: (ig 0-3, jg 2-3); needs B-jh1 (+A-h1 rides along) ----
    if (more) { asm volatile("s_waitcnt vmcnt(1)" ::: "memory"); }
    else      { asm volatile("s_waitcnt vmcnt(0)" ::: "memory"); }
    __builtin_amdgcn_s_barrier();
    asm volatile("" ::: "memory");
    if (more) stageB(t + 1, 0);
#pragma unroll
    for (int jp = 0; jp < 2; ++jp)
#pragma unroll
      for (int kk = 0; kk < 2; ++kk) bF[jp][kk] = rdB(Bt, 2 + jp, kk);
    __builtin_amdgcn_s_setprio(1);
#pragma unroll
    for (int ip = 0; ip < 4; ++ip)
#pragma unroll
      for (int jp = 0; jp < 2; ++jp)
#pragma unroll
        for (int kk = 0; kk < 2; ++kk)
          acc[ip][2 + jp] = MFMA(aF[ip][kk], bF[jp][kk], acc[ip][2 + jp], 0, 0, 0);
    __builtin_amdgcn_s_setprio(0);

    // ---- phase 3: (ig 4-6, jg 2-3); A-h1 landed per ph2 wait+barrier ----
    if (more) stageB(t + 1, 1);
#pragma unroll
    for (int ip = 0; ip < 3; ++ip)
#pragma unroll
      for (int kk = 0; kk < 2; ++kk) aF[ip][kk] = rdA(At, 4 + ip, kk);
    __builtin_amdgcn_s_setprio(1);
#pragma unroll
    for (int ip = 0; ip < 3; ++ip)
#pragma unroll
      for (int jp = 0; jp < 2; ++jp)
#pragma unroll
        for (int kk = 0; kk < 2; ++kk)
          acc[4 + ip][2 + jp] = MFMA(aF[ip][kk], bF[jp][kk], acc[4 + ip][2 + jp], 0, 0, 0);
    __builtin_amdgcn_s_setprio(0);

    // ---- phase 4: (ig 4-6, jg 0-1); B-jh0 re-read ----
    if (more) stageA(t + 1, 1);
#pragma unroll
    for (int jp = 0; jp < 2; ++jp)
#pragma unroll
      for (int kk = 0; kk < 2; ++kk) bF[jp][kk] = rdB(Bt, jp, kk);
    __builtin_amdgcn_s_setprio(1);
#pragma unroll
    for (int ip = 0; ip < 3; ++ip)
#pragma unroll
      for (int jp = 0; jp < 2; ++jp)
#pragma unroll
        for (int kk = 0; kk < 2; ++kk)
          acc[4 + ip][jp] = MFMA(aF[ip][kk], bF[jp][kk], acc[4 + ip][jp], 0, 0, 0);
    __builtin_amdgcn_s_setprio(0);
  }

  // epilogue
  const float* bs = (EPI == 3 && head) ? bias2 : bias;
  float* of = (EPI == 3 && head) ? outf2 : outf;
#pragma unroll
  for (int jg = 0; jg < 4; ++jg) {
    int col = wid * 64 + jg * 16 + (lane & 15);
    float bb = bs[col];
#pragma unroll
    for (int ig = 0; ig < 7; ++ig) {
      int rbase = row0 + ig * 16 + (lane >> 4) * 4;
      f32x4 v = acc[ig][jg];
#pragma unroll
      for (int r = 0; r < 4; ++r) {
        int row = rbase + r;
        if (row < N_NODES) {
          float f = v[r] + bb;
          if (EPI == 0) {
            f = fmaxf(f, 0.f);
            outb[(size_t)row * DIM + col] = f2bf(f);
          } else if (EPI == 1) {
            outf[(size_t)row * DIM + col] = f;
            outb[(size_t)row * DIM + col] = f2bf(f);
          } else {
            of[(size_t)row * DIM + col] = fmaxf(f, 0.f);
          }
        }
      }
    }
  }
}

// ---------------- launch ----------------
extern "C" void kernel_launch(void* const* d_in, const int* in_sizes, int n_in,
                              void* d_out, int out_size, void* d_ws, size_t ws_size,
                              hipStream_t stream) {
  (void)in_sizes; (void)n_in; (void)out_size; (void)ws_size;
  const float* x   = (const float*)d_in[0];
  const int*   ei  = (const int*)d_in[1];
  const float* Wl0 = (const float*)d_in[2];
  const float* bl0 = (const float*)d_in[3];
  const float* Wr0 = (const float*)d_in[4];
  const float* Wl1 = (const float*)d_in[5];
  const float* bl1 = (const float*)d_in[6];
  const float* Wr1 = (const float*)d_in[7];
  const float* Wv  = (const float*)d_in[8];
  const float* bv  = (const float*)d_in[9];
  const float* Wt  = (const float*)d_in[10];
  const float* bt  = (const float*)d_in[11];
  const int* srcI = ei;
  const int* dstI = ei + N_EDGES;

  float* out_h = (float*)d_out;
  float* out_v = out_h + (size_t)N_NODES * DIM;
  float* out_t = out_v + (size_t)N_NODES * DIM;
  u16* meanb  = (u16*)out_v;  // scratch: bf16 mean buffer (consumed before final write)
  u16* hrelub = (u16*)out_t;  // scratch: bf16 relu(h) buffer

  uint8_t* p = (uint8_t*)d_ws;
  auto carve = [&](size_t bytes) -> uint8_t* {
    uint8_t* r = p; p += (bytes + 1023) & ~(size_t)1023; return r;
  };
  int*   deg  = (int*)carve((size_t)N_NODES * 4);
  int*   offs = (int*)carve((size_t)(N_NODES + 1) * 4);
  int*   pos  = (int*)carve((size_t)N_NODES * 4);
  float* invd = (float*)carve((size_t)N_NODES * 4);
  int*   srcs = (int*)carve((size_t)N_EDGES * 4);
  u16* Wl0b = (u16*)carve(512 * 512 * 2);
  u16* Wr0b = (u16*)carve(512 * 512 * 2);
  u16* Wl1b = (u16*)carve(512 * 512 * 2);
  u16* Wr1b = (u16*)carve(512 * 512 * 2);
  u16* Wvb  = (u16*)carve(512 * 512 * 2);
  u16* Wtb  = (u16*)carve(512 * 512 * 2);
  u16* xb   = (u16*)carve((size_t)N_NODES * DIM * 2);  // x bf16, later h bf16

  const int EB = (N_EDGES + 255) / 256;

  // zero deg with a custom kernel: the rocclr fillBufferAligned blit path
  // costs ~175 us per dispatch here regardless of size (measured r2).
  k_zero<<<49, 256, 0, stream>>>((int4*)deg);

  // fused: cvt_x + hist + 6x weight transpose
  k_prep<<<12500, 256, 0, stream>>>(x, xb, dstI, deg,
                                    Wl0, Wr0, Wl1, Wr1, Wv, Wt,
                                    Wl0b, Wr0b, Wl1b, Wr1b, Wvb, Wtb);
  k_scan<<<1, 1024, 0, stream>>>(deg, offs, pos, invd);
  k_scatter<<<EB, 256, 0, stream>>>(srcI, dstI, pos, srcs);

  const int GB = 448;  // 448 row tiles of 112 rows (448*112 = 50176)

  // layer 0: mean-agg(xb) -> meanb ; h0 = relu(mean@Wl0 + x@Wr0 + bl0) -> hrelub (bf16)
  k_agg_bf16<<<12500, 256, 0, stream>>>(xb, offs, srcs, invd, meanb);
  k_gemm112<0><<<GB, 512, 0, stream>>>(meanb, Wl0b, xb, Wr0b, bl0, nullptr,
                                       nullptr, nullptr, hrelub, 16);

  // layer 1: mean-agg(hrelub) -> meanb ; h = mean@Wl1 + h0@Wr1 + bl1 -> out_h (f32) + xb (bf16)
  k_agg_bf16<<<12500, 256, 0, stream>>>(hrelub, offs, srcs, invd, meanb);
  k_gemm112<1><<<GB, 512, 0, stream>>>(meanb, Wl1b, hrelub, Wr1b, bl1, nullptr,
                                       out_h, nullptr, xb, 16);

  // fused heads: relu(h@Wv + bv) -> out_v ; relu(h@Wt + bt) -> out_t
  k_gemm112<3><<<896, 512, 0, stream>>>(xb, Wvb, nullptr, Wtb, bv, bt,
                                        out_v, out_t, nullptr, 8);
}

// Round 4
// 646.744 us; speedup vs baseline: 1.0452x; 1.0030x over previous
//
#include <hip/hip_runtime.h>
#include <hip/hip_bf16.h>
#include <stdint.h>

#define N_NODES 50000
#define N_EDGES 500000
#define DIM 512

typedef unsigned short u16;
typedef unsigned int u32;
typedef __bf16 bf16x8 __attribute__((ext_vector_type(8)));
typedef float f32x4 __attribute__((ext_vector_type(4)));

static __device__ __forceinline__ u16 f2bf(float f) {
  union { __bf16 b; u16 u; } cv; cv.b = (__bf16)f; return cv.u;
}
static __device__ __forceinline__ float bf2f(u16 u) {
  union { u16 u; __bf16 b; } cv; cv.u = u; return (float)cv.b;
}

// ---------------- deg zero (replaces pathological hipMemsetAsync blit) -------
__global__ void k_zero(int4* __restrict__ deg4) {
  int t = blockIdx.x * 256 + threadIdx.x;
  if (t < 12500) deg4[t] = make_int4(0, 0, 0, 0);  // 12500*16B = 200000B exact
}

// ---------------- CSR build ----------------
__global__ __launch_bounds__(1024) void k_scan(const int* __restrict__ deg,
                                               int* __restrict__ offs,
                                               int* __restrict__ pos,
                                               float* __restrict__ invd) {
  __shared__ int sums[1024];
  const int tid = threadIdx.x;
  const int CH = 49;  // 1024*49 = 50176 >= 50000
  int lo = tid * CH;
  int hi = lo + CH; if (hi > N_NODES) hi = N_NODES;
  if (lo > N_NODES) lo = N_NODES;
  int s = 0;
  for (int i = lo; i < hi; ++i) s += deg[i];
  sums[tid] = s;
  __syncthreads();
  for (int off = 1; off < 1024; off <<= 1) {
    int t = (tid >= off) ? sums[tid - off] : 0;
    __syncthreads();
    sums[tid] += t;
    __syncthreads();
  }
  int run = sums[tid] - s;  // exclusive prefix of this chunk
  for (int i = lo; i < hi; ++i) {
    int d = deg[i];
    offs[i] = run; pos[i] = run;
    invd[i] = 1.0f / (float)((d > 1) ? d : 1);
    run += d;
  }
  if (tid == 1023) offs[N_NODES] = run;
}

// srcs stores src*DIM (u16-element offset) so agg skips the multiply
__global__ void k_scatter(const int* __restrict__ src, const int* __restrict__ dst,
                          int* __restrict__ pos, int* __restrict__ srcs) {
  int e = blockIdx.x * blockDim.x + threadIdx.x;
  if (e < N_EDGES) {
    int p = atomicAdd(&pos[dst[e]], 1);
    srcs[p] = src[e] * DIM;
  }
}

// ---------------- fused prep: cvt_x + edge histogram + 6x weight transpose ----
__global__ __launch_bounds__(256) void k_prep(
    const float* __restrict__ x, u16* __restrict__ xb,
    const int* __restrict__ dst, int* __restrict__ deg,
    const float* __restrict__ Wa, const float* __restrict__ Wb,
    const float* __restrict__ Wc, const float* __restrict__ Wd,
    const float* __restrict__ We, const float* __restrict__ Wf,
    u16* __restrict__ Oa, u16* __restrict__ Ob, u16* __restrict__ Oc,
    u16* __restrict__ Od, u16* __restrict__ Oe, u16* __restrict__ Of) {
  __shared__ u16 tbuf[64][66];
  const int t = blockIdx.x * 256 + threadIdx.x;

  // --- cvt_x: 8 floats -> 8 bf16 per thread ---
  const float4* p = (const float4*)(x + (size_t)t * 8);
  float4 a = p[0], b = p[1];
  uint4 o;
  o.x = (u32)f2bf(a.x) | ((u32)f2bf(a.y) << 16);
  o.y = (u32)f2bf(a.z) | ((u32)f2bf(a.w) << 16);
  o.z = (u32)f2bf(b.x) | ((u32)f2bf(b.y) << 16);
  o.w = (u32)f2bf(b.z) | ((u32)f2bf(b.w) << 16);
  *(uint4*)(xb + (size_t)t * 8) = o;

  // --- edge degree histogram ---
  if (t < N_EDGES) atomicAdd(&deg[dst[t]], 1);

  // --- weight transpose (last 384 blocks) ---
  const int wb = (int)blockIdx.x - (12500 - 384);
  if (wb >= 0) {
    const float* W; u16* O;
    switch (wb / 64) {
      case 0: W = Wa; O = Oa; break;
      case 1: W = Wb; O = Ob; break;
      case 2: W = Wc; O = Oc; break;
      case 3: W = Wd; O = Od; break;
      case 4: W = We; O = Oe; break;
      default: W = Wf; O = Of; break;
    }
    const int rem = wb & 63;
    const int k0 = (rem & 7) * 64, n0 = (rem >> 3) * 64;
    const int lr = threadIdx.x & 63, wr = threadIdx.x >> 6;
#pragma unroll
    for (int rr = 0; rr < 16; ++rr) {
      int k = k0 + wr * 16 + rr;
      tbuf[lr][wr * 16 + rr] = f2bf(W[(size_t)k * 512 + n0 + lr]);
    }
    __syncthreads();
#pragma unroll
    for (int rr = 0; rr < 16; ++rr) {
      int n = n0 + wr * 16 + rr;
      O[(size_t)n * 512 + k0 + lr] = tbuf[wr * 16 + rr][lr];
    }
  }
}

// ---------------- aggregation: one wave per node, bf16 gather ----------------
// 8-wide edge unroll (8 outstanding 1KB row-loads/wave) with two independent
// accumulator banks; probes latency-vs-fabric-floor for the random gather.
#define ACCB(A, q)                                              \
  A[0] += bf2f((q).x & 0xffff); A[1] += bf2f((u16)((q).x >> 16)); \
  A[2] += bf2f((q).y & 0xffff); A[3] += bf2f((u16)((q).y >> 16)); \
  A[4] += bf2f((q).z & 0xffff); A[5] += bf2f((u16)((q).z >> 16)); \
  A[6] += bf2f((q).w & 0xffff); A[7] += bf2f((u16)((q).w >> 16));

__global__ __launch_bounds__(256) void k_agg_bf16(
    const u16* __restrict__ hb, const int* __restrict__ offs,
    const int* __restrict__ srcs, const float* __restrict__ invd,
    u16* __restrict__ outb) {
  int node = blockIdx.x * 4 + (threadIdx.x >> 6);
  int lane = threadIdx.x & 63;
  if (node >= N_NODES) return;
  int s0 = offs[node], s1 = offs[node + 1];
  float acc[8] = {0, 0, 0, 0, 0, 0, 0, 0};
  float acd[8] = {0, 0, 0, 0, 0, 0, 0, 0};
  const u16* hl = hb + lane * 8;
  int i = s0;
  for (; i + 8 <= s1; i += 8) {
    int sa = srcs[i], sb = srcs[i + 1], sc = srcs[i + 2], sd = srcs[i + 3];
    int se = srcs[i + 4], sf = srcs[i + 5], sg = srcs[i + 6], sh = srcs[i + 7];
    uint4 qa = *(const uint4*)(hl + sa);
    uint4 qb = *(const uint4*)(hl + sb);
    uint4 qc = *(const uint4*)(hl + sc);
    uint4 qd = *(const uint4*)(hl + sd);
    uint4 qe = *(const uint4*)(hl + se);
    uint4 qf = *(const uint4*)(hl + sf);
    uint4 qg = *(const uint4*)(hl + sg);
    uint4 qh = *(const uint4*)(hl + sh);
    ACCB(acc, qa) ACCB(acd, qb) ACCB(acc, qc) ACCB(acd, qd)
    ACCB(acc, qe) ACCB(acd, qf) ACCB(acc, qg) ACCB(acd, qh)
  }
  if (i + 4 <= s1) {
    int sa = srcs[i], sb = srcs[i + 1], sc = srcs[i + 2], sd = srcs[i + 3];
    uint4 qa = *(const uint4*)(hl + sa);
    uint4 qb = *(const uint4*)(hl + sb);
    uint4 qc = *(const uint4*)(hl + sc);
    uint4 qd = *(const uint4*)(hl + sd);
    ACCB(acc, qa) ACCB(acd, qb) ACCB(acc, qc) ACCB(acd, qd)
    i += 4;
  }
  if (i + 2 <= s1) {
    int sa = srcs[i], sb = srcs[i + 1];
    uint4 qa = *(const uint4*)(hl + sa);
    uint4 qb = *(const uint4*)(hl + sb);
    ACCB(acc, qa) ACCB(acd, qb)
    i += 2;
  }
  if (i < s1) {
    int sa = srcs[i];
    uint4 qa = *(const uint4*)(hl + sa);
    ACCB(acc, qa)
  }
  float iv = invd[node];
#pragma unroll
  for (int k = 0; k < 8; ++k) acc[k] = (acc[k] + acd[k]) * iv;
  uint4 o;
  o.x = (u32)f2bf(acc[0]) | ((u32)f2bf(acc[1]) << 16);
  o.y = (u32)f2bf(acc[2]) | ((u32)f2bf(acc[3]) << 16);
  o.z = (u32)f2bf(acc[4]) | ((u32)f2bf(acc[5]) << 16);
  o.w = (u32)f2bf(acc[6]) | ((u32)f2bf(acc[7]) << 16);
  *(uint4*)(outb + (size_t)node * DIM + lane * 8) = o;
}

// ---------------- GEMM: 112x512 tile, BK=64, 8 waves, 4-phase pipeline --------
// (unchanged from round 3 — see comments there)
#define MFMA __builtin_amdgcn_mfma_f32_16x16x32_bf16
#define BUFU 39936  // u16 per buffer: A 7168 + B 32768

template <int EPI>
__global__ __launch_bounds__(512, 2) void k_gemm112(
    const u16* __restrict__ A1, const u16* __restrict__ W1,
    const u16* __restrict__ A2, const u16* __restrict__ W2,
    const float* __restrict__ bias, const float* __restrict__ bias2,
    float* __restrict__ outf, float* __restrict__ outf2,
    u16* __restrict__ outb, int NT) {
  __shared__ u16 lds[2 * BUFU];  // 156 KB
  const int tid = threadIdx.x;
  const int wid = tid >> 6, lane = tid & 63;
  int head = 0, row0;
  if (EPI == 3) {
    head = (int)blockIdx.x & 1;
    row0 = ((int)blockIdx.x >> 1) * 112;
  } else {
    row0 = (int)blockIdx.x * 112;
  }
  const u16* BW = (EPI == 3) ? (head ? W2 : W1) : nullptr;

  f32x4 acc[7][4];
  const f32x4 z = {0.f, 0.f, 0.f, 0.f};
#pragma unroll
  for (int i = 0; i < 7; ++i)
#pragma unroll
    for (int j = 0; j < 4; ++j) acc[i][j] = z;

  const int ly = lane >> 3;
  const int schunk = (lane & 7) ^ ly;  // pre-swizzled global 16B-chunk

  // A tile rows 0..111 (+ ly per lane); half h: rows h*64 + w*8
  auto stageA = [&](int t, int h) {
    u16* tile = lds + (t & 1) * BUFU;
    const u16* G = (EPI == 3) ? A1 : ((t < 8) ? A1 : A2);
    int w = wid;
    if (h && w >= 6) w -= 2;  // duplicate rows 96..111 (same src+dest, benign)
    const int rb = h * 64 + w * 8;
    int rg = row0 + rb + ly;
    if (rg > N_NODES - 1) rg = N_NODES - 1;
    const u16* g = G + (size_t)rg * 512 + (t & 7) * 64 + schunk * 8;
    __builtin_amdgcn_global_load_lds(
        (const __attribute__((address_space(1))) void*)g,
        (__attribute__((address_space(3))) void*)(tile + rb * 64), 16, 0, 0);
  };

  // B tile rows 0..511; jh half = rows with (r&32)==jh*32
  auto stageB = [&](int t, int jh) {
    u16* tile = lds + (t & 1) * BUFU + 7168;
    const u16* G = (EPI == 3) ? BW : ((t < 8) ? W1 : W2);
    const int kofs = (t & 7) * 64 + schunk * 8;
#pragma unroll
    for (int u = 0; u < 4; ++u) {
      const int rb = u * 128 + (wid >> 2) * 64 + (wid & 3) * 8 + jh * 32;
      const u16* g = G + (size_t)(rb + ly) * 512 + kofs;
      __builtin_amdgcn_global_load_lds(
          (const __attribute__((address_space(1))) void*)g,
          (__attribute__((address_space(3))) void*)(tile + rb * 64), 16, 0, 0);
    }
  };

  auto rdA = [&](const u16* T_, int ig, int kk) -> bf16x8 {
    const int r = ig * 16 + (lane & 15);
    const int off = ((kk * 4 + (lane >> 4)) ^ (lane & 7)) * 8;
    return *(const bf16x8*)(T_ + r * 64 + off);
  };
  auto rdB = [&](const u16* T_, int jg, int kk) -> bf16x8 {
    const int r = wid * 64 + jg * 16 + (lane & 15);
    const int off = ((kk * 4 + (lane >> 4)) ^ (lane & 7)) * 8;
    return *(const bf16x8*)(T_ + r * 64 + off);
  };

  // prologue: tile 0, order A0, Bjh0, Bjh1, A1 (10 loads/wave)
  stageA(0, 0); stageB(0, 0); stageB(0, 1); stageA(0, 1);

  for (int t = 0; t < NT; ++t) {
    const u16* At = lds + (t & 1) * BUFU;
    const u16* Bt = At + 7168;
    const bool more = (t + 1 < NT);
    bf16x8 aF[4][2], bF[2][2];

    // ---- phase 1: (ig 0-3, jg 0-1); needs A-h0 + B-jh0 ----
    asm volatile("s_waitcnt vmcnt(5)" ::: "memory");
    __builtin_amdgcn_s_barrier();
    asm volatile("" ::: "memory");
    if (more) stageA(t + 1, 0);
#pragma unroll
    for (int ip = 0; ip < 4; ++ip)
#pragma unroll
      for (int kk = 0; kk < 2; ++kk) aF[ip][kk] = rdA(At, ip, kk);
#pragma unroll
    for (int jp = 0; jp < 2; ++jp)
#pragma unroll
      for (int kk = 0; kk < 2; ++kk) bF[jp][kk] = rdB(Bt, jp, kk);
    __builtin_amdgcn_s_setprio(1);
#pragma unroll
    for (int ip = 0; ip < 4; ++ip)
#pragma unroll
      for (int jp = 0; jp < 2; ++jp)
#pragma unroll
        for (int kk = 0; kk < 2; ++kk)
          acc[ip][jp] = MFMA(aF[ip][kk], bF[jp][kk], acc[ip][jp], 0, 0, 0);
    __builtin_amdgcn_s_setprio(0);

    // ---- phase 2: (ig 0-3, jg 2-3); needs B-jh1 (+A-h1 rides along) ----
    if (more) { asm volatile("s_waitcnt vmcnt(1)" ::: "memory"); }
    else      { asm volatile("s_waitcnt vmcnt(0)" ::: "memory"); }
    __builtin_amdgcn_s_barrier();
    asm volatile("" ::: "memory");
    if (more) stageB(t + 1, 0);
#pragma unroll
    for (int jp = 0; jp < 2; ++jp)
#pragma unroll
      for (int kk = 0; kk < 2; ++kk) bF[jp][kk] = rdB(Bt, 2 + jp, kk);
    __builtin_amdgcn_s_setprio(1);
#pragma unroll
    for (int ip = 0; ip < 4; ++ip)
#pragma unroll
      for (int jp = 0; jp < 2; ++jp)
#pragma unroll
        for (int kk = 0; kk < 2; ++kk)
          acc[ip][2 + jp] = MFMA(aF[ip][kk], bF[jp][kk], acc[ip][2 + jp], 0, 0, 0);
    __builtin_amdgcn_s_setprio(0);

    // ---- phase 3: (ig 4-6, jg 2-3); A-h1 landed per ph2 wait+barrier ----
    if (more) stageB(t + 1, 1);
#pragma unroll
    for (int ip = 0; ip < 3; ++ip)
#pragma unroll
      for (int kk = 0; kk < 2; ++kk) aF[ip][kk] = rdA(At, 4 + ip, kk);
    __builtin_amdgcn_s_setprio(1);
#pragma unroll
    for (int ip = 0; ip < 3; ++ip)
#pragma unroll
      for (int jp = 0; jp < 2; ++jp)
#pragma unroll
        for (int kk = 0; kk < 2; ++kk)
          acc[4 + ip][2 + jp] = MFMA(aF[ip][kk], bF[jp][kk], acc[4 + ip][2 + jp], 0, 0, 0);
    __builtin_amdgcn_s_setprio(0);

    // ---- phase 4: (ig 4-6, jg 0-1); B-jh0 re-read ----
    if (more) stageA(t + 1, 1);
#pragma unroll
    for (int jp = 0; jp < 2; ++jp)
#pragma unroll
      for (int kk = 0; kk < 2; ++kk) bF[jp][kk] = rdB(Bt, jp, kk);
    __builtin_amdgcn_s_setprio(1);
#pragma unroll
    for (int ip = 0; ip < 3; ++ip)
#pragma unroll
      for (int jp = 0; jp < 2; ++jp)
#pragma unroll
        for (int kk = 0; kk < 2; ++kk)
          acc[4 + ip][jp] = MFMA(aF[ip][kk], bF[jp][kk], acc[4 + ip][jp], 0, 0, 0);
    __builtin_amdgcn_s_setprio(0);
  }

  // epilogue
  const float* bs = (EPI == 3 && head) ? bias2 : bias;
  float* of = (EPI == 3 && head) ? outf2 : outf;
#pragma unroll
  for (int jg = 0; jg < 4; ++jg) {
    int col = wid * 64 + jg * 16 + (lane & 15);
    float bb = bs[col];
#pragma unroll
    for (int ig = 0; ig < 7; ++ig) {
      int rbase = row0 + ig * 16 + (lane >> 4) * 4;
      f32x4 v = acc[ig][jg];
#pragma unroll
      for (int r = 0; r < 4; ++r) {
        int row = rbase + r;
        if (row < N_NODES) {
          float f = v[r] + bb;
          if (EPI == 0) {
            f = fmaxf(f, 0.f);
            outb[(size_t)row * DIM + col] = f2bf(f);
          } else if (EPI == 1) {
            outf[(size_t)row * DIM + col] = f;
            outb[(size_t)row * DIM + col] = f2bf(f);
          } else {
            of[(size_t)row * DIM + col] = fmaxf(f, 0.f);
          }
        }
      }
    }
  }
}

// ---------------- launch ----------------
extern "C" void kernel_launch(void* const* d_in, const int* in_sizes, int n_in,
                              void* d_out, int out_size, void* d_ws, size_t ws_size,
                              hipStream_t stream) {
  (void)in_sizes; (void)n_in; (void)out_size; (void)ws_size;
  const float* x   = (const float*)d_in[0];
  const int*   ei  = (const int*)d_in[1];
  const float* Wl0 = (const float*)d_in[2];
  const float* bl0 = (const float*)d_in[3];
  const float* Wr0 = (const float*)d_in[4];
  const float* Wl1 = (const float*)d_in[5];
  const float* bl1 = (const float*)d_in[6];
  const float* Wr1 = (const float*)d_in[7];
  const float* Wv  = (const float*)d_in[8];
  const float* bv  = (const float*)d_in[9];
  const float* Wt  = (const float*)d_in[10];
  const float* bt  = (const float*)d_in[11];
  const int* srcI = ei;
  const int* dstI = ei + N_EDGES;

  float* out_h = (float*)d_out;
  float* out_v = out_h + (size_t)N_NODES * DIM;
  float* out_t = out_v + (size_t)N_NODES * DIM;
  u16* meanb  = (u16*)out_v;  // scratch: bf16 mean buffer (consumed before final write)
  u16* hrelub = (u16*)out_t;  // scratch: bf16 relu(h) buffer

  uint8_t* p = (uint8_t*)d_ws;
  auto carve = [&](size_t bytes) -> uint8_t* {
    uint8_t* r = p; p += (bytes + 1023) & ~(size_t)1023; return r;
  };
  int*   deg  = (int*)carve((size_t)N_NODES * 4);
  int*   offs = (int*)carve((size_t)(N_NODES + 1) * 4);
  int*   pos  = (int*)carve((size_t)N_NODES * 4);
  float* invd = (float*)carve((size_t)N_NODES * 4);
  int*   srcs = (int*)carve((size_t)N_EDGES * 4);
  u16* Wl0b = (u16*)carve(512 * 512 * 2);
  u16* Wr0b = (u16*)carve(512 * 512 * 2);
  u16* Wl1b = (u16*)carve(512 * 512 * 2);
  u16* Wr1b = (u16*)carve(512 * 512 * 2);
  u16* Wvb  = (u16*)carve(512 * 512 * 2);
  u16* Wtb  = (u16*)carve(512 * 512 * 2);
  u16* xb   = (u16*)carve((size_t)N_NODES * DIM * 2);  // x bf16, later h bf16

  const int EB = (N_EDGES + 255) / 256;

  // zero deg with a custom kernel (rocclr blit path avoided)
  k_zero<<<49, 256, 0, stream>>>((int4*)deg);

  // fused: cvt_x + hist + 6x weight transpose
  k_prep<<<12500, 256, 0, stream>>>(x, xb, dstI, deg,
                                    Wl0, Wr0, Wl1, Wr1, Wv, Wt,
                                    Wl0b, Wr0b, Wl1b, Wr1b, Wvb, Wtb);
  k_scan<<<1, 1024, 0, stream>>>(deg, offs, pos, invd);
  k_scatter<<<EB, 256, 0, stream>>>(srcI, dstI, pos, srcs);

  const int GB = 448;  // 448 row tiles of 112 rows (448*112 = 50176)

  // layer 0: mean-agg(xb) -> meanb ; h0 = relu(mean@Wl0 + x@Wr0 + bl0) -> hrelub (bf16)
  k_agg_bf16<<<12500, 256, 0, stream>>>(xb, offs, srcs, invd, meanb);
  k_gemm112<0><<<GB, 512, 0, stream>>>(meanb, Wl0b, xb, Wr0b, bl0, nullptr,
                                       nullptr, nullptr, hrelub, 16);

  // layer 1: mean-agg(hrelub) -> meanb ; h = mean@Wl1 + h0@Wr1 + bl1 -> out_h (f32) + xb (bf16)
  k_agg_bf16<<<12500, 256, 0, stream>>>(hrelub, offs, srcs, invd, meanb);
  k_gemm112<1><<<GB, 512, 0, stream>>>(meanb, Wl1b, hrelub, Wr1b, bl1, nullptr,
                                       out_h, nullptr, xb, 16);

  // fused heads: relu(h@Wv + bv) -> out_v ; relu(h@Wt + bt) -> out_t
  k_gemm112<3><<<896, 512, 0, stream>>>(xb, Wvb, nullptr, Wtb, bv, bt,
                                        out_v, out_t, nullptr, 8);
}